// Round 1
// baseline (350.528 us; speedup 1.0000x reference)
//
#include <hip/hip_runtime.h>
#include <hip/hip_bf16.h>
#include <math.h>

#define N_ROWS 8192
#define DIM    512

typedef __bf16 bf16x8 __attribute__((ext_vector_type(8)));
typedef float  floatx4 __attribute__((ext_vector_type(4)));

__device__ __forceinline__ unsigned short f2bf_rne(float x) {
    union { float f; unsigned u; } v; v.f = x;
    unsigned r = v.u + 0x7FFFu + ((v.u >> 16) & 1u);
    return (unsigned short)(r >> 16);
}

// async global->LDS, 16B per lane. LDS dest must be wave-uniform base + lane*16.
__device__ __forceinline__ void async_cp16(const void* g, void* l) {
    __builtin_amdgcn_global_load_lds(
        (const __attribute__((address_space(1))) unsigned int*)g,
        (__attribute__((address_space(3))) unsigned int*)l,
        16, 0, 0);
}

// Kernel 1: one wave per row. Compute fp32 sq_norm, convert row to bf16.
__global__ __launch_bounds__(256) void fs_norm_convert(
    const float* __restrict__ F, unsigned short* __restrict__ Fb,
    float* __restrict__ sn) {
    const int wave = threadIdx.x >> 6;
    const int lane = threadIdx.x & 63;
    const int row  = blockIdx.x * 4 + wave;

    const float4* src = reinterpret_cast<const float4*>(F + (size_t)row * DIM) + lane * 2;
    float4 x0 = src[0];
    float4 x1 = src[1];

    float ss = x0.x*x0.x + x0.y*x0.y + x0.z*x0.z + x0.w*x0.w
             + x1.x*x1.x + x1.y*x1.y + x1.z*x1.z + x1.w*x1.w;

    uint4 p;
    p.x = (unsigned)f2bf_rne(x0.x) | ((unsigned)f2bf_rne(x0.y) << 16);
    p.y = (unsigned)f2bf_rne(x0.z) | ((unsigned)f2bf_rne(x0.w) << 16);
    p.z = (unsigned)f2bf_rne(x1.x) | ((unsigned)f2bf_rne(x1.y) << 16);
    p.w = (unsigned)f2bf_rne(x1.z) | ((unsigned)f2bf_rne(x1.w) << 16);
    reinterpret_cast<uint4*>(Fb + (size_t)row * DIM)[lane] = p;

    #pragma unroll
    for (int off = 32; off > 0; off >>= 1) ss += __shfl_down(ss, off);
    if (lane == 0) sn[row] = ss;
}

// Kernel 2: C = F * F^T in bf16 MFMA, epilogue -sqrt(max(sn_i+sn_j-2c,0)).
// 128x128 block tile, BK=32, 4 waves in 2x2, each wave 64x64 (4x4 MFMA tiles).
__global__ __launch_bounds__(256) void fs_gemm(
    const unsigned short* __restrict__ Fb, const float* __restrict__ sn,
    float* __restrict__ out) {
    __shared__ unsigned short As[128 * 32];   // row-major, no pad (global_load_lds)
    __shared__ unsigned short Bs[128 * 32];

    const int tid  = threadIdx.x;
    const int lane = tid & 63;
    const int wave = tid >> 6;
    const int wr   = wave >> 1;      // wave row 0..1
    const int wc   = wave & 1;       // wave col 0..1
    const int quad = lane >> 4;      // 0..3
    const int l16  = lane & 15;

    const int bRow = blockIdx.y * 128;
    const int bCol = blockIdx.x * 128;

    floatx4 acc[4][4];
    #pragma unroll
    for (int i = 0; i < 4; ++i)
        #pragma unroll
        for (int j = 0; j < 4; ++j)
            acc[i][j] = floatx4{0.f, 0.f, 0.f, 0.f};

    // Staging: thread tid covers A rows tid/4 and 64+tid/4, k-cols (tid%4)*8..+8
    const int sRow = tid >> 2;
    const int sCol = (tid & 3) * 8;
    const unsigned short* gA = Fb + (size_t)(bRow + sRow) * DIM + sCol;
    const unsigned short* gB = Fb + (size_t)(bCol + sRow) * DIM + sCol;
    const size_t half = (size_t)64 * DIM;

    unsigned short* ldsA = As + tid * 8;          // = row*32 + col, row-major
    unsigned short* ldsB = Bs + tid * 8;

    for (int k0 = 0; k0 < DIM; k0 += 32) {
        async_cp16(gA,        ldsA);
        async_cp16(gA + half, ldsA + 2048);
        async_cp16(gB,        ldsB);
        async_cp16(gB + half, ldsB + 2048);
        gA += 32; gB += 32;
        __syncthreads();   // drains vmcnt(0): LDS tiles complete

        bf16x8 af[4], bf[4];
        #pragma unroll
        for (int t = 0; t < 4; ++t) {
            af[t] = *reinterpret_cast<const bf16x8*>(
                As + ((wr * 64 + t * 16 + l16) * 32 + quad * 8));
            bf[t] = *reinterpret_cast<const bf16x8*>(
                Bs + ((wc * 64 + t * 16 + l16) * 32 + quad * 8));
        }
        #pragma unroll
        for (int i = 0; i < 4; ++i)
            #pragma unroll
            for (int j = 0; j < 4; ++j)
                acc[i][j] = __builtin_amdgcn_mfma_f32_16x16x32_bf16(
                    af[i], bf[j], acc[i][j], 0, 0, 0);
        __syncthreads();
    }

    // Epilogue. C/D layout: col = lane&15, row = quad*4 + reg.
    const int row0 = bRow + wr * 64;
    const int col0 = bCol + wc * 64;
    float snc[4];
    #pragma unroll
    for (int j = 0; j < 4; ++j) snc[j] = sn[col0 + j * 16 + l16];

    #pragma unroll
    for (int i = 0; i < 4; ++i) {
        #pragma unroll
        for (int r = 0; r < 4; ++r) {
            const int row = row0 + i * 16 + quad * 4 + r;
            const float snr = sn[row];
            float* orow = out + (size_t)row * N_ROWS;
            #pragma unroll
            for (int j = 0; j < 4; ++j) {
                const int col = col0 + j * 16 + l16;
                float v = snr + snc[j] - 2.0f * acc[i][j][r];
                v = fmaxf(v, 0.0f);
                orow[col] = (row == col) ? 0.0f : -sqrtf(v);
            }
        }
    }
}

extern "C" void kernel_launch(void* const* d_in, const int* in_sizes, int n_in,
                              void* d_out, int out_size, void* d_ws, size_t ws_size,
                              hipStream_t stream) {
    const float* F = (const float*)d_in[0];
    float* out = (float*)d_out;

    unsigned short* Fb = (unsigned short*)d_ws;                       // 8 MiB bf16 copy
    float* sn = (float*)((char*)d_ws + (size_t)N_ROWS * DIM * 2);     // 32 KiB norms

    fs_norm_convert<<<N_ROWS / 4, 256, 0, stream>>>(F, Fb, sn);

    dim3 grid(N_ROWS / 128, N_ROWS / 128);
    fs_gemm<<<grid, 256, 0, stream>>>(Fb, sn, out);
}